// Round 4
// baseline (432.157 us; speedup 1.0000x reference)
//
#include <hip/hip_runtime.h>
#include <stdint.h>

// Problem constants (fixed by reference setup_inputs)
#define BB 8192
#define DD 4096
#define HH 2048
#define DW (DD / 32)   // 128 words per x / Wb row
#define HW (HH / 32)   // 64 words per h row / Wcol column

// ---------------------------------------------------------------------------
// pack_W_rows -> WrowT4: layout [k4 0..31][j 0..2047] of uint4 = words
// {4k4..4k4+3} of binarized W row j. Consecutive j contiguous -> the main
// kernel's per-lane uint4 load is coalesced across the wave.
// ---------------------------------------------------------------------------
__global__ void k_pack_wrow(const float* __restrict__ W,
                            uint32_t* __restrict__ WrowT4) {
    int flat = blockIdx.x * blockDim.x + threadIdx.x;   // over HH*DW = 262144
    int j = flat >> 7;
    int k = flat & (DW - 1);
    const float4* p = (const float4*)(W + (size_t)j * DD + 32 * k);
    uint32_t w = 0;
#pragma unroll
    for (int q = 0; q < 8; ++q) {
        float4 v = p[q];
        w |= (v.x >= 0.5f ? 1u : 0u) << (4 * q + 0);
        w |= (v.y >= 0.5f ? 1u : 0u) << (4 * q + 1);
        w |= (v.z >= 0.5f ? 1u : 0u) << (4 * q + 2);
        w |= (v.w >= 0.5f ? 1u : 0u) << (4 * q + 3);
    }
    WrowT4[((size_t)(k >> 2) * HH + j) * 4 + (k & 3)] = w;
}

// ---------------------------------------------------------------------------
// pack_W_cols -> WcolT: word-plane layout [kw 0..63][d 0..4095], uint32.
// WcolT[kw][d] bit i = (W[(kw*32+i)][d] >= 0.5). Plane 0 (16KB) stays L1-
// resident in the main kernel's phase 3.
// ---------------------------------------------------------------------------
__global__ void k_pack_wcol(const float* __restrict__ W,
                            uint32_t* __restrict__ WcolT) {
    int flat = blockIdx.x * blockDim.x + threadIdx.x;   // over HW*DD = 262144
    int kw = flat >> 12;
    int d  = flat & (DD - 1);
    uint32_t w = 0;
#pragma unroll
    for (int i = 0; i < 32; ++i) {
        float v = W[(size_t)(kw * 32 + i) * DD + d];
        w |= (v >= 0.5f ? 1u : 0u) << i;
    }
    WcolT[(size_t)kw * DD + d] = w;
}

// ---------------------------------------------------------------------------
// Integer thresholds: smallest integer c with (float)c + bias >= 1.0f.
// Counts <= 4096 are exact in fp32 so the integer compare is exact.
// ---------------------------------------------------------------------------
__device__ __forceinline__ int calc_thresh(float bias) {
    float need = 1.0f - bias;
    if (!(need == need)) return 2000000000;       // NaN bias: never fires
    if (need > 1.0e9f)  return 2000000000;
    if (need < -1.0e9f) return -2000000000;
    int t = (int)ceilf(need);
#pragma unroll
    for (int it = 0; it < 2; ++it)
        if ((float)(t - 1) + bias >= 1.0f) t--;
#pragma unroll
    for (int it = 0; it < 2; ++it)
        if ((float)t + bias < 1.0f) t++;
    return t;
}

__global__ void k_thresh(const float* __restrict__ b_enc,
                         const float* __restrict__ b0,
                         const float* __restrict__ b3,
                         int* __restrict__ t1, int* __restrict__ t2) {
    int tid = blockIdx.x * blockDim.x + threadIdx.x;  // HH + DD threads
    if (tid < HH) {
        t1[tid] = calc_thresh(b_enc[tid] + b0[tid]);
    } else {
        int d = tid - HH;
        t2[d] = calc_thresh(b3[d]);
    }
}

// ---------------------------------------------------------------------------
// Fused main kernel: one block (256 threads) per batch row b.
// Phase 1: pack x row -> LDS xw[128] (ballot, coalesced 4B/lane reads).
// Phase 2: h bits via early-exit popcount vs WrowT4 (L2-resident, 16B/lane
//          coalesced) -> LDS hw[64]. Early exit exact (count monotone).
// Phase 3: out row via word-plane WcolT (plane 0 L1-resident), 4 outputs
//          per thread, float4 coalesced stores. Typically exits at kw=0.
// ---------------------------------------------------------------------------
__global__ void __launch_bounds__(256)
k_main(const float* __restrict__ x,
       const uint4* __restrict__ WrowT4,
       const uint32_t* __restrict__ WcolT,
       const int* __restrict__ t1,
       const int* __restrict__ t2,
       float* __restrict__ out) {
    __shared__ uint32_t xw[DW];   // 128 words = packed x row
    __shared__ uint32_t hw[HW];   // 64 words  = packed h row

    const int b   = blockIdx.x;
    const int tid = threadIdx.x;
    const int wv  = tid >> 6;     // wave id 0..3
    const int ln  = tid & 63;     // lane

    // ---- phase 1: pack x[b][*] into xw ----
    const float* xr = x + (size_t)b * DD;
#pragma unroll
    for (int it = 0; it < 16; ++it) {
        int d = it * 256 + tid;                     // coalesced
        unsigned long long m = __ballot(xr[d] >= 0.5f);
        if (ln == 0) {
            int wd = it * 8 + wv * 2;
            xw[wd]     = (uint32_t)m;
            xw[wd + 1] = (uint32_t)(m >> 32);
        }
    }
    __syncthreads();

    // ---- phase 2: h[b][j] for j = jj*256 + tid ----
    for (int jj = 0; jj < 8; ++jj) {
        int j = jj * 256 + tid;
        int t = t1[j];
        int c = 0;
        if (t > 0) {
            for (int k4 = 0; k4 < DW / 4; ++k4) {   // <=32 iters, early exit
                uint4 w = WrowT4[(size_t)k4 * HH + j];        // coalesced
                uint4 a = *(const uint4*)(xw + 4 * k4);       // LDS broadcast
                c += __popc(a.x & w.x) + __popc(a.y & w.y) +
                     __popc(a.z & w.z) + __popc(a.w & w.w);
                if (c >= t) break;
            }
        }
        unsigned long long m = __ballot(c >= t);
        if (ln == 0) {
            int wd = jj * 8 + wv * 2;
            hw[wd]     = (uint32_t)m;
            hw[wd + 1] = (uint32_t)(m >> 32);
        }
    }
    __syncthreads();

    // ---- phase 3: out[b][*], 4 outputs per thread per iter ----
    float* orow = out + (size_t)b * DD;
#pragma unroll
    for (int it = 0; it < 4; ++it) {
        int q  = it * 256 + tid;                    // uint4 index 0..1023
        int d0 = q * 4;
        int4 tt = *(const int4*)(t2 + d0);
        int c0 = 0, c1 = 0, c2 = 0, c3 = 0;
        for (int kw = 0; kw < HW; ++kw) {
            if (c0 >= tt.x && c1 >= tt.y && c2 >= tt.z && c3 >= tt.w) break;
            uint32_t h = hw[kw];                               // LDS broadcast
            uint4 w = *(const uint4*)(WcolT + (size_t)kw * DD + d0); // coalesced
            c0 += __popc(h & w.x);
            c1 += __popc(h & w.y);
            c2 += __popc(h & w.z);
            c3 += __popc(h & w.w);
        }
        float4 r;
        r.x = (c0 >= tt.x) ? 1.0f : 0.0f;
        r.y = (c1 >= tt.y) ? 1.0f : 0.0f;
        r.z = (c2 >= tt.z) ? 1.0f : 0.0f;
        r.w = (c3 >= tt.w) ? 1.0f : 0.0f;
        *(float4*)(orow + d0) = r;
    }
}

// ---------------------------------------------------------------------------
extern "C" void kernel_launch(void* const* d_in, const int* in_sizes, int n_in,
                              void* d_out, int out_size, void* d_ws, size_t ws_size,
                              hipStream_t stream) {
    const float* x     = (const float*)d_in[0];   // [B, D]
    const float* W     = (const float*)d_in[1];   // [H, D]
    const float* b_enc = (const float*)d_in[2];   // [H]
    const float* b0    = (const float*)d_in[3];   // [H]
    const float* b3    = (const float*)d_in[4];   // [D]
    float* out = (float*)d_out;                   // [B, D]

    // Workspace layout (16B-aligned offsets)
    char* ws = (char*)d_ws;
    uint32_t* WrowT4 = (uint32_t*)(ws);                       // 1 MB
    uint32_t* WcolT  = (uint32_t*)(ws + (1u << 20));          // 1 MB
    int*      t1     = (int*)(ws + (2u << 20));               // 8 KB
    int*      t2     = (int*)(ws + (2u << 20) + 8192);        // 16 KB

    const int BLK = 256;

    k_pack_wrow<<<(HH * DW) / BLK, BLK, 0, stream>>>(W, WrowT4);
    k_pack_wcol<<<(HW * DD) / BLK, BLK, 0, stream>>>(W, WcolT);
    k_thresh  <<<(HH + DD) / BLK, BLK, 0, stream>>>(b_enc, b0, b3, t1, t2);
    k_main    <<<BB, BLK, 0, stream>>>(x, (const uint4*)WrowT4, WcolT, t1, t2, out);
}

// Round 7
// 325.008 us; speedup vs baseline: 1.3297x; 1.3297x over previous
//
#include <hip/hip_runtime.h>
#include <stdint.h>

// Problem constants (fixed by reference setup_inputs)
#define BB 8192
#define DD 4096
#define HH 2048
#define DW (DD / 32)   // 128 words per x / Wb row
#define HW (HH / 32)   // 64 words per h row / Wcol column

// ---------------------------------------------------------------------------
// pack_x: one thread per 32-bit WORD. Thread reads 128B contiguous floats,
// builds one word. Wave covers 8KB contiguous input; word writes coalesced.
// ---------------------------------------------------------------------------
__global__ void k_pack_x(const float* __restrict__ x,
                         uint32_t* __restrict__ xb) {
    int flat = blockIdx.x * blockDim.x + threadIdx.x;   // over BB*DW
    int b  = flat >> 7;
    int wd = flat & (DW - 1);
    const float4* p = (const float4*)(x + (size_t)b * DD + 32 * wd);
    uint32_t w = 0;
#pragma unroll
    for (int q = 0; q < 8; ++q) {
        float4 v = p[q];
        w |= (v.x >= 0.5f ? 1u : 0u) << (4 * q + 0);
        w |= (v.y >= 0.5f ? 1u : 0u) << (4 * q + 1);
        w |= (v.z >= 0.5f ? 1u : 0u) << (4 * q + 2);
        w |= (v.w >= 0.5f ? 1u : 0u) << (4 * q + 3);
    }
    xb[flat] = w;
}

// ---------------------------------------------------------------------------
// pack_W_rows -> WrowT4: layout [k4 0..31][j 0..2047] of uint4 = words
// {4k4..4k4+3} of binarized W row j. Consecutive j contiguous -> gemm1's
// per-lane uint4 load is coalesced across the wave.
// ---------------------------------------------------------------------------
__global__ void k_pack_wrow(const float* __restrict__ W,
                            uint32_t* __restrict__ WrowT4) {
    int flat = blockIdx.x * blockDim.x + threadIdx.x;   // over HH*DW = 262144
    int j = flat >> 7;
    int k = flat & (DW - 1);
    const float4* p = (const float4*)(W + (size_t)j * DD + 32 * k);
    uint32_t w = 0;
#pragma unroll
    for (int q = 0; q < 8; ++q) {
        float4 v = p[q];
        w |= (v.x >= 0.5f ? 1u : 0u) << (4 * q + 0);
        w |= (v.y >= 0.5f ? 1u : 0u) << (4 * q + 1);
        w |= (v.z >= 0.5f ? 1u : 0u) << (4 * q + 2);
        w |= (v.w >= 0.5f ? 1u : 0u) << (4 * q + 3);
    }
    WrowT4[((size_t)(k >> 2) * HH + j) * 4 + (k & 3)] = w;
}

// ---------------------------------------------------------------------------
// pack_W_cols -> WcolT: word-plane layout [kw 0..63][d 0..4095], uint32.
// WcolT[kw][d] bit i = (W[(kw*32+i)][d] >= 0.5). Plane 0 (16KB) stays L1-
// resident in gemm2. Lanes take consecutive d -> coalesced.
// ---------------------------------------------------------------------------
__global__ void k_pack_wcol(const float* __restrict__ W,
                            uint32_t* __restrict__ WcolT) {
    int flat = blockIdx.x * blockDim.x + threadIdx.x;   // over HW*DD = 262144
    int kw = flat >> 12;
    int d  = flat & (DD - 1);
    uint32_t w = 0;
#pragma unroll
    for (int i = 0; i < 32; ++i) {
        float v = W[(size_t)(kw * 32 + i) * DD + d];
        w |= (v >= 0.5f ? 1u : 0u) << i;
    }
    WcolT[(size_t)kw * DD + d] = w;
}

// ---------------------------------------------------------------------------
// Integer thresholds: smallest integer c with (float)c + bias >= 1.0f.
// Counts <= 4096 are exact in fp32 so the integer compare is exact.
// ---------------------------------------------------------------------------
__device__ __forceinline__ int calc_thresh(float bias) {
    float need = 1.0f - bias;
    if (!(need == need)) return 2000000000;       // NaN bias: never fires
    if (need > 1.0e9f)  return 2000000000;
    if (need < -1.0e9f) return -2000000000;
    int t = (int)ceilf(need);
#pragma unroll
    for (int it = 0; it < 2; ++it)
        if ((float)(t - 1) + bias >= 1.0f) t--;
#pragma unroll
    for (int it = 0; it < 2; ++it)
        if ((float)t + bias < 1.0f) t++;
    return t;
}

__global__ void k_thresh(const float* __restrict__ b_enc,
                         const float* __restrict__ b0,
                         const float* __restrict__ b3,
                         int* __restrict__ t1, int* __restrict__ t2) {
    int tid = blockIdx.x * blockDim.x + threadIdx.x;  // HH + DD threads
    if (tid < HH) {
        t1[tid] = calc_thresh(b_enc[tid] + b0[tid]);
    } else {
        int d = tid - HH;
        t2[d] = calc_thresh(b3[d]);
    }
}

// ---------------------------------------------------------------------------
// GEMM1: h[b][j] = popcount(x_row & W_row_j) >= t1[j]. One thread per (b,j),
// 16.7M threads of pure TLP (latency-bound early-exit loops want waves, not
// fusion — R4 lesson). Batch = 2 uint4 (256 bits) per early-exit check:
// halves the dependent L2-load chain, 2-way load ILP inside each batch.
// Early exit exact (count monotone). h bits ballot-packed.
// ---------------------------------------------------------------------------
__global__ void k_gemm1(const uint32_t* __restrict__ xb,
                        const uint4* __restrict__ WrowT4,
                        const int* __restrict__ t1,
                        uint32_t* __restrict__ hb) {
    int flat = blockIdx.x * blockDim.x + threadIdx.x;   // over BB*HH
    int b = flat >> 11;
    int j = flat & (HH - 1);
    const uint32_t* xr = xb + (size_t)b * DW;
    int t = t1[j];
    int c = 0;
    if (t > 0) {
        for (int k8 = 0; k8 < DW / 8; ++k8) {     // 16 iters of 256 bits
            uint4 w0 = WrowT4[(size_t)(2 * k8) * HH + j];       // coalesced
            uint4 w1 = WrowT4[(size_t)(2 * k8 + 1) * HH + j];   // coalesced
            uint4 a0 = *(const uint4*)(xr + 8 * k8);            // broadcast
            uint4 a1 = *(const uint4*)(xr + 8 * k8 + 4);
            c += __popc(a0.x & w0.x) + __popc(a0.y & w0.y) +
                 __popc(a0.z & w0.z) + __popc(a0.w & w0.w) +
                 __popc(a1.x & w1.x) + __popc(a1.y & w1.y) +
                 __popc(a1.z & w1.z) + __popc(a1.w & w1.w);
            if (c >= t) break;
        }
    }
    unsigned long long m = __ballot(c >= t);
    if ((threadIdx.x & 63) == 0) {
        int jw = j >> 5;           // even
        hb[(size_t)b * HW + jw]     = (uint32_t)m;
        hb[(size_t)b * HW + jw + 1] = (uint32_t)(m >> 32);
    }
}

// ---------------------------------------------------------------------------
// GEMM2: out[b][d] = popcount(h_row & W_col_d) >= t2[d]. One thread per 4
// outputs: per iter one uint4 of word kw for d0..d0+3 (coalesced; plane 0
// is 16KB -> L1-resident), h word broadcast. Typically exits on kw=0.
// float4 coalesced stores.
// ---------------------------------------------------------------------------
__global__ void k_gemm2(const uint32_t* __restrict__ hb,
                        const uint32_t* __restrict__ WcolT,
                        const int* __restrict__ t2,
                        float* __restrict__ out) {
    int flat = blockIdx.x * blockDim.x + threadIdx.x;   // over BB*DD/4
    int b  = flat >> 10;
    int d0 = (flat & 1023) * 4;
    const uint32_t* hr = hb + (size_t)b * HW;
    int4 tt = *(const int4*)(t2 + d0);
    int c0 = 0, c1 = 0, c2 = 0, c3 = 0;
    for (int kw = 0; kw < HW; ++kw) {
        uint32_t h = hr[kw];                                // broadcast
        uint4 w = *(const uint4*)(WcolT + (size_t)kw * DD + d0); // coalesced
        c0 += __popc(h & w.x);
        c1 += __popc(h & w.y);
        c2 += __popc(h & w.z);
        c3 += __popc(h & w.w);
        if (c0 >= tt.x && c1 >= tt.y && c2 >= tt.z && c3 >= tt.w) break;
    }
    float4 r;
    r.x = (c0 >= tt.x) ? 1.0f : 0.0f;
    r.y = (c1 >= tt.y) ? 1.0f : 0.0f;
    r.z = (c2 >= tt.z) ? 1.0f : 0.0f;
    r.w = (c3 >= tt.w) ? 1.0f : 0.0f;
    *(float4*)(out + (size_t)b * DD + d0) = r;
}

// ---------------------------------------------------------------------------
extern "C" void kernel_launch(void* const* d_in, const int* in_sizes, int n_in,
                              void* d_out, int out_size, void* d_ws, size_t ws_size,
                              hipStream_t stream) {
    const float* x     = (const float*)d_in[0];   // [B, D]
    const float* W     = (const float*)d_in[1];   // [H, D]
    const float* b_enc = (const float*)d_in[2];   // [H]
    const float* b0    = (const float*)d_in[3];   // [H]
    const float* b3    = (const float*)d_in[4];   // [D]
    float* out = (float*)d_out;                   // [B, D]

    // Workspace layout (16B-aligned offsets)
    char* ws = (char*)d_ws;
    uint32_t* WrowT4 = (uint32_t*)(ws);                       // 1 MB
    uint32_t* WcolT  = (uint32_t*)(ws + (1u << 20));          // 1 MB
    uint32_t* xb     = (uint32_t*)(ws + (2u << 20));          // 4 MB
    uint32_t* hb     = (uint32_t*)(ws + (6u << 20));          // 2 MB
    int*      t1     = (int*)(ws + (8u << 20));               // 8 KB
    int*      t2     = (int*)(ws + (8u << 20) + 8192);        // 16 KB

    const int BLK = 256;

    k_pack_wrow<<<(HH * DW) / BLK, BLK, 0, stream>>>(W, WrowT4);
    k_pack_wcol<<<(HW * DD) / BLK, BLK, 0, stream>>>(W, WcolT);
    k_pack_x  <<<(BB * DW) / BLK, BLK, 0, stream>>>(x, xb);
    k_thresh  <<<(HH + DD) / BLK, BLK, 0, stream>>>(b_enc, b0, b3, t1, t2);
    k_gemm1   <<<(BB * HH) / BLK, BLK, 0, stream>>>(xb, (const uint4*)WrowT4, t1, hb);
    k_gemm2   <<<(BB * DD / 4) / BLK, BLK, 0, stream>>>(hb, WcolT, t2, out);
}

// Round 8
// 304.520 us; speedup vs baseline: 1.4191x; 1.0673x over previous
//
#include <hip/hip_runtime.h>
#include <stdint.h>

// Problem constants (fixed by reference setup_inputs)
#define BB 8192
#define DD 4096
#define HH 2048
#define DW (DD / 32)   // 128 words per x / Wb row
#define HW (HH / 32)   // 64 words per h row / Wcol column

// ---------------------------------------------------------------------------
// pack_x: one thread per 32-bit WORD. Thread reads 128B contiguous floats,
// builds one word. Wave covers 8KB contiguous input; word writes coalesced.
// ---------------------------------------------------------------------------
__global__ void k_pack_x(const float* __restrict__ x,
                         uint32_t* __restrict__ xb) {
    int flat = blockIdx.x * blockDim.x + threadIdx.x;   // over BB*DW
    int b  = flat >> 7;
    int wd = flat & (DW - 1);
    const float4* p = (const float4*)(x + (size_t)b * DD + 32 * wd);
    uint32_t w = 0;
#pragma unroll
    for (int q = 0; q < 8; ++q) {
        float4 v = p[q];
        w |= (v.x >= 0.5f ? 1u : 0u) << (4 * q + 0);
        w |= (v.y >= 0.5f ? 1u : 0u) << (4 * q + 1);
        w |= (v.z >= 0.5f ? 1u : 0u) << (4 * q + 2);
        w |= (v.w >= 0.5f ? 1u : 0u) << (4 * q + 3);
    }
    xb[flat] = w;
}

// ---------------------------------------------------------------------------
// Single-pass W pack: reads W ONCE, emits both layouts.
//   WrowT4 [k4 0..31][j 0..2047] uint4  (gemm1: consecutive j coalesced)
//   WcolT  [kw 0..63][d 0..4095] uint32 (gemm2: word-plane, plane L1-res.)
// Block = 256 threads handles a 32j x 256d tile:
//   phase 1: thread (r=tid>>3, wi=tid&7) packs 32 floats of row j0+r -> word,
//            stores WrowT4 entry + LDS[r][wi].
//   phase 2: thread (d_local=tid) builds WcolT[jt][d0+d_local] by gathering
//            bit d_local from the 32 rows (LDS broadcast reads).
// ---------------------------------------------------------------------------
__global__ void __launch_bounds__(256)
k_pack_w(const float* __restrict__ W,
         uint32_t* __restrict__ WrowT4,
         uint32_t* __restrict__ WcolT) {
    __shared__ uint32_t lds[32][8];
    int tile = blockIdx.x;            // 64*16 = 1024 tiles
    int jt = tile >> 4;               // 0..63   (kw plane)
    int dt = tile & 15;               // 0..15
    int j0 = jt * 32;
    int d0 = dt * 256;

    // phase 1: row words
    int r  = threadIdx.x >> 3;        // 0..31
    int wi = threadIdx.x & 7;         // 0..7
    const float4* p = (const float4*)(W + (size_t)(j0 + r) * DD + d0 + wi * 32);
    uint32_t w = 0;
#pragma unroll
    for (int q = 0; q < 8; ++q) {
        float4 v = p[q];
        w |= (v.x >= 0.5f ? 1u : 0u) << (4 * q + 0);
        w |= (v.y >= 0.5f ? 1u : 0u) << (4 * q + 1);
        w |= (v.z >= 0.5f ? 1u : 0u) << (4 * q + 2);
        w |= (v.w >= 0.5f ? 1u : 0u) << (4 * q + 3);
    }
    int k = dt * 8 + wi;              // word index 0..127
    WrowT4[((size_t)(k >> 2) * HH + (j0 + r)) * 4 + (k & 3)] = w;
    lds[r][wi] = w;
    __syncthreads();

    // phase 2: column words (32x32 bit transpose via LDS broadcasts)
    int dl = threadIdx.x;             // 0..255
    int wsel = dl >> 5;               // which word of the row covers this d
    int bsel = dl & 31;               // bit within that word
    uint32_t cw = 0;
#pragma unroll
    for (int i = 0; i < 32; ++i) {
        cw |= ((lds[i][wsel] >> bsel) & 1u) << i;
    }
    WcolT[(size_t)jt * DD + d0 + dl] = cw;
}

// ---------------------------------------------------------------------------
// Integer thresholds: smallest integer c with (float)c + bias >= 1.0f.
// Counts <= 4096 are exact in fp32 so the integer compare is exact.
// ---------------------------------------------------------------------------
__device__ __forceinline__ int calc_thresh(float bias) {
    float need = 1.0f - bias;
    if (!(need == need)) return 2000000000;       // NaN bias: never fires
    if (need > 1.0e9f)  return 2000000000;
    if (need < -1.0e9f) return -2000000000;
    int t = (int)ceilf(need);
#pragma unroll
    for (int it = 0; it < 2; ++it)
        if ((float)(t - 1) + bias >= 1.0f) t--;
#pragma unroll
    for (int it = 0; it < 2; ++it)
        if ((float)t + bias < 1.0f) t++;
    return t;
}

__global__ void k_thresh(const float* __restrict__ b_enc,
                         const float* __restrict__ b0,
                         const float* __restrict__ b3,
                         int* __restrict__ t1, int* __restrict__ t2) {
    int tid = blockIdx.x * blockDim.x + threadIdx.x;  // HH + DD threads
    if (tid < HH) {
        t1[tid] = calc_thresh(b_enc[tid] + b0[tid]);
    } else {
        int d = tid - HH;
        t2[d] = calc_thresh(b3[d]);
    }
}

// ---------------------------------------------------------------------------
// GEMM1: one thread = one j x FOUR b's. The 32B weight load per iteration is
// shared across 4 dot-products -> WrowT4 L2 read traffic cut ~4x vs 1-b/thread
// (R7 analysis: gemm1 was ~590MB of L2 reads). xb row loads are wave-uniform
// (bg is block-uniform) -> L1/scalar broadcast. Early exit when all 4 counters
// reach t (exact; counts monotone). h bits ballot-packed per b.
// ---------------------------------------------------------------------------
__global__ void k_gemm1(const uint32_t* __restrict__ xb,
                        const uint4* __restrict__ WrowT4,
                        const int* __restrict__ t1,
                        uint32_t* __restrict__ hb) {
    int flat = blockIdx.x * blockDim.x + threadIdx.x;   // over (BB/4)*HH
    int bg = flat >> 11;            // b-group 0..2047 (block-uniform)
    int j  = flat & (HH - 1);
    int b0 = bg * 4;
    const uint32_t* xr0 = xb + (size_t)(b0 + 0) * DW;
    const uint32_t* xr1 = xb + (size_t)(b0 + 1) * DW;
    const uint32_t* xr2 = xb + (size_t)(b0 + 2) * DW;
    const uint32_t* xr3 = xb + (size_t)(b0 + 3) * DW;
    int t = t1[j];
    int c0 = 0, c1 = 0, c2 = 0, c3 = 0;
    if (t > 0) {
        for (int k8 = 0; k8 < DW / 8; ++k8) {     // 16 iters of 256 bits
            uint4 w0 = WrowT4[(size_t)(2 * k8) * HH + j];       // coalesced
            uint4 w1 = WrowT4[(size_t)(2 * k8 + 1) * HH + j];   // coalesced
            uint4 a0, a1;
            a0 = *(const uint4*)(xr0 + 8 * k8); a1 = *(const uint4*)(xr0 + 8 * k8 + 4);
            c0 += __popc(a0.x & w0.x) + __popc(a0.y & w0.y) +
                  __popc(a0.z & w0.z) + __popc(a0.w & w0.w) +
                  __popc(a1.x & w1.x) + __popc(a1.y & w1.y) +
                  __popc(a1.z & w1.z) + __popc(a1.w & w1.w);
            a0 = *(const uint4*)(xr1 + 8 * k8); a1 = *(const uint4*)(xr1 + 8 * k8 + 4);
            c1 += __popc(a0.x & w0.x) + __popc(a0.y & w0.y) +
                  __popc(a0.z & w0.z) + __popc(a0.w & w0.w) +
                  __popc(a1.x & w1.x) + __popc(a1.y & w1.y) +
                  __popc(a1.z & w1.z) + __popc(a1.w & w1.w);
            a0 = *(const uint4*)(xr2 + 8 * k8); a1 = *(const uint4*)(xr2 + 8 * k8 + 4);
            c2 += __popc(a0.x & w0.x) + __popc(a0.y & w0.y) +
                  __popc(a0.z & w0.z) + __popc(a0.w & w0.w) +
                  __popc(a1.x & w1.x) + __popc(a1.y & w1.y) +
                  __popc(a1.z & w1.z) + __popc(a1.w & w1.w);
            a0 = *(const uint4*)(xr3 + 8 * k8); a1 = *(const uint4*)(xr3 + 8 * k8 + 4);
            c3 += __popc(a0.x & w0.x) + __popc(a0.y & w0.y) +
                  __popc(a0.z & w0.z) + __popc(a0.w & w0.w) +
                  __popc(a1.x & w1.x) + __popc(a1.y & w1.y) +
                  __popc(a1.z & w1.z) + __popc(a1.w & w1.w);
            if (c0 >= t && c1 >= t && c2 >= t && c3 >= t) break;
        }
    }
    int jw = (j >> 5) & ~1;          // even word index for this wave's lane0
    unsigned long long m;
    m = __ballot(c0 >= t);
    if ((threadIdx.x & 63) == 0) {
        hb[(size_t)(b0 + 0) * HW + jw]     = (uint32_t)m;
        hb[(size_t)(b0 + 0) * HW + jw + 1] = (uint32_t)(m >> 32);
    }
    m = __ballot(c1 >= t);
    if ((threadIdx.x & 63) == 0) {
        hb[(size_t)(b0 + 1) * HW + jw]     = (uint32_t)m;
        hb[(size_t)(b0 + 1) * HW + jw + 1] = (uint32_t)(m >> 32);
    }
    m = __ballot(c2 >= t);
    if ((threadIdx.x & 63) == 0) {
        hb[(size_t)(b0 + 2) * HW + jw]     = (uint32_t)m;
        hb[(size_t)(b0 + 2) * HW + jw + 1] = (uint32_t)(m >> 32);
    }
    m = __ballot(c3 >= t);
    if ((threadIdx.x & 63) == 0) {
        hb[(size_t)(b0 + 3) * HW + jw]     = (uint32_t)m;
        hb[(size_t)(b0 + 3) * HW + jw + 1] = (uint32_t)(m >> 32);
    }
}

// ---------------------------------------------------------------------------
// GEMM2: out[b][d] = popcount(h_row & W_col_d) >= t2[d]. One thread per 4
// outputs: per iter one uint4 of word kw for d0..d0+3 (coalesced; plane 0
// is 16KB -> L1-resident), h word broadcast. Typically exits on kw=0.
// float4 coalesced stores.
// ---------------------------------------------------------------------------
__global__ void k_gemm2(const uint32_t* __restrict__ hb,
                        const uint32_t* __restrict__ WcolT,
                        const int* __restrict__ t2,
                        float* __restrict__ out) {
    int flat = blockIdx.x * blockDim.x + threadIdx.x;   // over BB*DD/4
    int b  = flat >> 10;
    int d0 = (flat & 1023) * 4;
    const uint32_t* hr = hb + (size_t)b * HW;
    int4 tt = *(const int4*)(t2 + d0);
    int c0 = 0, c1 = 0, c2 = 0, c3 = 0;
    for (int kw = 0; kw < HW; ++kw) {
        uint32_t h = hr[kw];                                // broadcast
        uint4 w = *(const uint4*)(WcolT + (size_t)kw * DD + d0); // coalesced
        c0 += __popc(h & w.x);
        c1 += __popc(h & w.y);
        c2 += __popc(h & w.z);
        c3 += __popc(h & w.w);
        if (c0 >= tt.x && c1 >= tt.y && c2 >= tt.z && c3 >= tt.w) break;
    }
    float4 r;
    r.x = (c0 >= tt.x) ? 1.0f : 0.0f;
    r.y = (c1 >= tt.y) ? 1.0f : 0.0f;
    r.z = (c2 >= tt.z) ? 1.0f : 0.0f;
    r.w = (c3 >= tt.w) ? 1.0f : 0.0f;
    *(float4*)(out + (size_t)b * DD + d0) = r;
}

// ---------------------------------------------------------------------------
extern "C" void kernel_launch(void* const* d_in, const int* in_sizes, int n_in,
                              void* d_out, int out_size, void* d_ws, size_t ws_size,
                              hipStream_t stream) {
    const float* x     = (const float*)d_in[0];   // [B, D]
    const float* W     = (const float*)d_in[1];   // [H, D]
    const float* b_enc = (const float*)d_in[2];   // [H]
    const float* b0    = (const float*)d_in[3];   // [H]
    const float* b3    = (const float*)d_in[4];   // [D]
    float* out = (float*)d_out;                   // [B, D]

    // Workspace layout (16B-aligned offsets)
    char* ws = (char*)d_ws;
    uint32_t* WrowT4 = (uint32_t*)(ws);                       // 1 MB
    uint32_t* WcolT  = (uint32_t*)(ws + (1u << 20));          // 1 MB
    uint32_t* xb     = (uint32_t*)(ws + (2u << 20));          // 4 MB
    uint32_t* hb     = (uint32_t*)(ws + (6u << 20));          // 2 MB
    int*      t1     = (int*)(ws + (8u << 20));               // 8 KB
    int*      t2     = (int*)(ws + (8u << 20) + 8192);        // 16 KB

    const int BLK = 256;

    k_pack_w <<<(HH / 32) * (DD / 256), BLK, 0, stream>>>(W, WrowT4, WcolT);
    k_pack_x <<<(BB * DW) / BLK, BLK, 0, stream>>>(x, xb);
    k_thresh <<<(HH + DD) / BLK, BLK, 0, stream>>>(b_enc, b0, b3, t1, t2);
    k_gemm1  <<<((BB / 4) * HH) / BLK, BLK, 0, stream>>>(xb, (const uint4*)WrowT4, t1, hb);
    k_gemm2  <<<(BB * DD / 4) / BLK, BLK, 0, stream>>>(hb, WcolT, t2, out);
}

// Round 9
// 301.229 us; speedup vs baseline: 1.4346x; 1.0109x over previous
//
#include <hip/hip_runtime.h>
#include <stdint.h>

// Problem constants (fixed by reference setup_inputs)
#define BB 8192
#define DD 4096
#define HH 2048
#define DW (DD / 32)   // 128 words per x / Wb row
#define HW (HH / 32)   // 64 words per h row / Wcol column

// grid partition for the merged prologue kernel
#define NB_PACKW  ((HH / 32) * (DD / 256))   // 1024
#define NB_PACKX  ((BB * DW) / 256)          // 4096
#define NB_THRESH ((HH + DD) / 256)          // 24

// ---------------------------------------------------------------------------
// Integer thresholds: smallest integer c with (float)c + bias >= 1.0f.
// Counts <= 4096 are exact in fp32 so the integer compare is exact.
// ---------------------------------------------------------------------------
__device__ __forceinline__ int calc_thresh(float bias) {
    float need = 1.0f - bias;
    if (!(need == need)) return 2000000000;       // NaN bias: never fires
    if (need > 1.0e9f)  return 2000000000;
    if (need < -1.0e9f) return -2000000000;
    int t = (int)ceilf(need);
#pragma unroll
    for (int it = 0; it < 2; ++it)
        if ((float)(t - 1) + bias >= 1.0f) t--;
#pragma unroll
    for (int it = 0; it < 2; ++it)
        if ((float)t + bias < 1.0f) t++;
    return t;
}

// ---------------------------------------------------------------------------
// Merged prologue: pack_w tiles + pack_x + thresholds in ONE launch
// (independent work; grid-partitioned by blockIdx so the small W-pack and
// threshold blocks co-run under the memory-bound x-pack instead of
// serializing as separate launches — R8 lesson: launches serialize on the
// stream even when independent).
// ---------------------------------------------------------------------------
__global__ void __launch_bounds__(256)
k_prep(const float* __restrict__ W,
       const float* __restrict__ x,
       const float* __restrict__ b_enc,
       const float* __restrict__ b0,
       const float* __restrict__ b3,
       uint32_t* __restrict__ WrowT4,
       uint32_t* __restrict__ WcolT,
       uint32_t* __restrict__ xb,
       int* __restrict__ t1, int* __restrict__ t2) {
    __shared__ uint32_t lds[32][8];
    int blk = blockIdx.x;

    if (blk < NB_PACKW) {
        // ---- W pack: 32j x 256d tile; read W once, emit both layouts ----
        int jt = blk >> 4;                // 0..63   (kw plane)
        int dt = blk & 15;                // 0..15
        int j0 = jt * 32;
        int d0 = dt * 256;

        int r  = threadIdx.x >> 3;        // 0..31
        int wi = threadIdx.x & 7;         // 0..7
        const float4* p = (const float4*)(W + (size_t)(j0 + r) * DD + d0 + wi * 32);
        uint32_t w = 0;
#pragma unroll
        for (int q = 0; q < 8; ++q) {
            float4 v = p[q];
            w |= (v.x >= 0.5f ? 1u : 0u) << (4 * q + 0);
            w |= (v.y >= 0.5f ? 1u : 0u) << (4 * q + 1);
            w |= (v.z >= 0.5f ? 1u : 0u) << (4 * q + 2);
            w |= (v.w >= 0.5f ? 1u : 0u) << (4 * q + 3);
        }
        int k = dt * 8 + wi;              // word index 0..127
        WrowT4[((size_t)(k >> 2) * HH + (j0 + r)) * 4 + (k & 3)] = w;
        lds[r][wi] = w;
        __syncthreads();

        // 32x32 bit transpose via LDS broadcasts -> column word-plane
        int dl = threadIdx.x;             // 0..255
        int wsel = dl >> 5;
        int bsel = dl & 31;
        uint32_t cw = 0;
#pragma unroll
        for (int i = 0; i < 32; ++i) {
            cw |= ((lds[i][wsel] >> bsel) & 1u) << i;
        }
        WcolT[(size_t)jt * DD + d0 + dl] = cw;

    } else if (blk < NB_PACKW + NB_PACKX) {
        // ---- x pack: one thread per word, 128B contiguous read ----
        int flat = (blk - NB_PACKW) * 256 + threadIdx.x;   // over BB*DW
        int b  = flat >> 7;
        int wd = flat & (DW - 1);
        const float4* p = (const float4*)(x + (size_t)b * DD + 32 * wd);
        uint32_t w = 0;
#pragma unroll
        for (int q = 0; q < 8; ++q) {
            float4 v = p[q];
            w |= (v.x >= 0.5f ? 1u : 0u) << (4 * q + 0);
            w |= (v.y >= 0.5f ? 1u : 0u) << (4 * q + 1);
            w |= (v.z >= 0.5f ? 1u : 0u) << (4 * q + 2);
            w |= (v.w >= 0.5f ? 1u : 0u) << (4 * q + 3);
        }
        xb[flat] = w;

    } else {
        // ---- thresholds ----
        int tid = (blk - NB_PACKW - NB_PACKX) * 256 + threadIdx.x; // < HH+DD
        if (tid < HH) {
            t1[tid] = calc_thresh(b_enc[tid] + b0[tid]);
        } else {
            int d = tid - HH;
            t2[d] = calc_thresh(b3[d]);
        }
    }
}

// ---------------------------------------------------------------------------
// GEMM1: one thread = one j x TWO b's. Weight load shared across 2 dots
// (L2 traffic ~2x down vs 1-b); wave tail halved vs 4-b (128 dot-products
// per wave instead of 256 gate the early exit — R8 theory: tail divergence,
// P(256-bit chunk < t=2 overlaps) ~ 1.2%/chunk, dominated wave iterations).
// Early exit exact (counts monotone). h bits ballot-packed per b.
// ---------------------------------------------------------------------------
__global__ void k_gemm1(const uint32_t* __restrict__ xb,
                        const uint4* __restrict__ WrowT4,
                        const int* __restrict__ t1,
                        uint32_t* __restrict__ hb) {
    int flat = blockIdx.x * blockDim.x + threadIdx.x;   // over (BB/2)*HH
    int bg = flat >> 11;            // b-pair 0..4095 (block-uniform)
    int j  = flat & (HH - 1);
    int b0 = bg * 2;
    const uint32_t* xr0 = xb + (size_t)(b0 + 0) * DW;
    const uint32_t* xr1 = xb + (size_t)(b0 + 1) * DW;
    int t = t1[j];
    int c0 = 0, c1 = 0;
    if (t > 0) {
        for (int k8 = 0; k8 < DW / 8; ++k8) {     // 16 iters of 256 bits
            uint4 w0 = WrowT4[(size_t)(2 * k8) * HH + j];       // coalesced
            uint4 w1 = WrowT4[(size_t)(2 * k8 + 1) * HH + j];   // coalesced
            uint4 a0, a1;
            a0 = *(const uint4*)(xr0 + 8 * k8); a1 = *(const uint4*)(xr0 + 8 * k8 + 4);
            c0 += __popc(a0.x & w0.x) + __popc(a0.y & w0.y) +
                  __popc(a0.z & w0.z) + __popc(a0.w & w0.w) +
                  __popc(a1.x & w1.x) + __popc(a1.y & w1.y) +
                  __popc(a1.z & w1.z) + __popc(a1.w & w1.w);
            a0 = *(const uint4*)(xr1 + 8 * k8); a1 = *(const uint4*)(xr1 + 8 * k8 + 4);
            c1 += __popc(a0.x & w0.x) + __popc(a0.y & w0.y) +
                  __popc(a0.z & w0.z) + __popc(a0.w & w0.w) +
                  __popc(a1.x & w1.x) + __popc(a1.y & w1.y) +
                  __popc(a1.z & w1.z) + __popc(a1.w & w1.w);
            if (c0 >= t && c1 >= t) break;
        }
    }
    int jw = (j >> 5) & ~1;          // even word index for this wave's lane0
    unsigned long long m;
    m = __ballot(c0 >= t);
    if ((threadIdx.x & 63) == 0) {
        hb[(size_t)(b0 + 0) * HW + jw]     = (uint32_t)m;
        hb[(size_t)(b0 + 0) * HW + jw + 1] = (uint32_t)(m >> 32);
    }
    m = __ballot(c1 >= t);
    if ((threadIdx.x & 63) == 0) {
        hb[(size_t)(b0 + 1) * HW + jw]     = (uint32_t)m;
        hb[(size_t)(b0 + 1) * HW + jw + 1] = (uint32_t)(m >> 32);
    }
}

// ---------------------------------------------------------------------------
// GEMM2: out[b][d] = popcount(h_row & W_col_d) >= t2[d]. One thread per 4
// outputs: per iter one uint4 of word kw for d0..d0+3 (coalesced; plane 0
// is 16KB -> L1-resident), h word broadcast. Typically exits on kw=0 ->
// write-bound (134 MB out) ~21us floor. float4 coalesced stores.
// ---------------------------------------------------------------------------
__global__ void k_gemm2(const uint32_t* __restrict__ hb,
                        const uint32_t* __restrict__ WcolT,
                        const int* __restrict__ t2,
                        float* __restrict__ out) {
    int flat = blockIdx.x * blockDim.x + threadIdx.x;   // over BB*DD/4
    int b  = flat >> 10;
    int d0 = (flat & 1023) * 4;
    const uint32_t* hr = hb + (size_t)b * HW;
    int4 tt = *(const int4*)(t2 + d0);
    int c0 = 0, c1 = 0, c2 = 0, c3 = 0;
    for (int kw = 0; kw < HW; ++kw) {
        uint32_t h = hr[kw];                                // broadcast
        uint4 w = *(const uint4*)(WcolT + (size_t)kw * DD + d0); // coalesced
        c0 += __popc(h & w.x);
        c1 += __popc(h & w.y);
        c2 += __popc(h & w.z);
        c3 += __popc(h & w.w);
        if (c0 >= tt.x && c1 >= tt.y && c2 >= tt.z && c3 >= tt.w) break;
    }
    float4 r;
    r.x = (c0 >= tt.x) ? 1.0f : 0.0f;
    r.y = (c1 >= tt.y) ? 1.0f : 0.0f;
    r.z = (c2 >= tt.z) ? 1.0f : 0.0f;
    r.w = (c3 >= tt.w) ? 1.0f : 0.0f;
    *(float4*)(out + (size_t)b * DD + d0) = r;
}

// ---------------------------------------------------------------------------
extern "C" void kernel_launch(void* const* d_in, const int* in_sizes, int n_in,
                              void* d_out, int out_size, void* d_ws, size_t ws_size,
                              hipStream_t stream) {
    const float* x     = (const float*)d_in[0];   // [B, D]
    const float* W     = (const float*)d_in[1];   // [H, D]
    const float* b_enc = (const float*)d_in[2];   // [H]
    const float* b0    = (const float*)d_in[3];   // [H]
    const float* b3    = (const float*)d_in[4];   // [D]
    float* out = (float*)d_out;                   // [B, D]

    // Workspace layout (16B-aligned offsets)
    char* ws = (char*)d_ws;
    uint32_t* WrowT4 = (uint32_t*)(ws);                       // 1 MB
    uint32_t* WcolT  = (uint32_t*)(ws + (1u << 20));          // 1 MB
    uint32_t* xb     = (uint32_t*)(ws + (2u << 20));          // 4 MB
    uint32_t* hb     = (uint32_t*)(ws + (6u << 20));          // 2 MB
    int*      t1     = (int*)(ws + (8u << 20));               // 8 KB
    int*      t2     = (int*)(ws + (8u << 20) + 8192);        // 16 KB

    const int BLK = 256;

    k_prep <<<NB_PACKW + NB_PACKX + NB_THRESH, BLK, 0, stream>>>(
        W, x, b_enc, b0, b3, WrowT4, WcolT, xb, t1, t2);
    k_gemm1<<<((BB / 2) * HH) / BLK, BLK, 0, stream>>>(
        xb, (const uint4*)WrowT4, t1, hb);
    k_gemm2<<<(BB * DD / 4) / BLK, BLK, 0, stream>>>(hb, WcolT, t2, out);
}